// Round 12
// baseline (964.581 us; speedup 1.0000x reference)
//
#include <hip/hip_runtime.h>
#include <stdint.h>

#define T_  4096
#define D_  1024
#define E_  8
#define F_  4096
#define H1_ 256
#define H2_ 64
#define SCALE_ 1.0f
#define NROW_ (2 * T_)
#define NT2_ 40   // max active 256-row m-tiles: 8192/256 + (E-1) = 39

typedef unsigned short ushort_t;
typedef unsigned int   uint32;
typedef __attribute__((ext_vector_type(8))) short  short8;
typedef __attribute__((ext_vector_type(4))) float  f32x4;
typedef __attribute__((ext_vector_type(8))) unsigned short us8;

// raw barrier: no compiler-inserted vmcnt(0) drain
#define BARRIER() do { asm volatile("" ::: "memory"); __builtin_amdgcn_s_barrier(); asm volatile("" ::: "memory"); } while (0)
#define WAITVM(N) asm volatile("s_waitcnt vmcnt(" #N ")" ::: "memory")

__device__ __forceinline__ ushort_t f2bf(float f) {
  uint32 u = __float_as_uint(f);
  u += 0x7FFFu + ((u >> 16) & 1u);   // RNE
  return (ushort_t)(u >> 16);
}
// jax.nn.gelu default = tanh approximation
__device__ __forceinline__ float gelu_tanh(float x) {
  float u = 0.7978845608028654f * (x + 0.044715f * x * x * x);
  float e = __expf(2.0f * u);
  return 0.5f * x * (1.0f + (1.0f - 2.0f / (e + 1.0f)));
}
__device__ __forceinline__ void gll16(const void* gptr, void* lptr) {
  void* g = const_cast<void*>(gptr);
  __builtin_amdgcn_global_load_lds((__attribute__((address_space(1))) void*)g,
                                   (__attribute__((address_space(3))) void*)lptr,
                                   16, 0, 0);
}

// 256x128 tile, BK=64. Staging per wave: 4 A-loads (rowfrags 2w,2w+1 x 2 ks)
// + 2 B-loads (rowfrag w x 2 ks) = 6 gll16 -> counted WAITVM(6).
__device__ __forceinline__ void stage6(const ushort_t* a0, const ushort_t* a1,
                                       const ushort_t* b0,
                                       short8 (*An)[16][64], short8 (*Bn)[8][64], int w) {
  gll16(a0,      &An[0][w * 2 + 0][0]);
  gll16(a0 + 32, &An[1][w * 2 + 0][0]);
  gll16(a1,      &An[0][w * 2 + 1][0]);
  gll16(a1 + 32, &An[1][w * 2 + 1][0]);
  gll16(b0,      &Bn[0][w][0]);
  gll16(b0 + 32, &Bn[1][w][0]);
}

// 8 waves (4M x 2N), per-wave 64x64 output: 32 MFMA per BK=64 step (monolithic;
// phase-split/setprio reverted -- measured -8% in round 10).
__device__ __forceinline__ void mfma_step32(const short8 (*Ac)[16][64], const short8 (*Bc)[8][64],
                                            int wr, int wc, int lane, f32x4 acc[4][4]) {
#pragma unroll
  for (int ks = 0; ks < 2; ++ks) {
    short8 af[4], bf4[4];
#pragma unroll
    for (int i = 0; i < 4; ++i) af[i] = Ac[ks][wr * 4 + i][lane];
#pragma unroll
    for (int j = 0; j < 4; ++j) bf4[j] = Bc[ks][wc * 4 + j][lane];
#pragma unroll
    for (int i = 0; i < 4; ++i)
#pragma unroll
      for (int j = 0; j < 4; ++j)
        acc[i][j] = __builtin_amdgcn_mfma_f32_16x16x32_bf16(af[i], bf4[j], acc[i][j], 0, 0, 0);
  }
}

// ---------------- h -> bf16 ----------------
__global__ void k_cvt_h(const float* __restrict__ h, ushort_t* __restrict__ hb) {
  int i = (blockIdx.x * 256 + threadIdx.x) * 8;
  float4 a = *(const float4*)(h + i);
  float4 b = *(const float4*)(h + i + 4);
  short8 v;
  v[0] = (short)f2bf(a.x); v[1] = (short)f2bf(a.y);
  v[2] = (short)f2bf(a.z); v[3] = (short)f2bf(a.w);
  v[4] = (short)f2bf(b.x); v[5] = (short)f2bf(b.y);
  v[6] = (short)f2bf(b.z); v[7] = (short)f2bf(b.w);
  *(short8*)(hb + i) = v;
}

// ---- transpose + cvt: in [E][R][C] f32 -> out [E][C][R] bf16, LDS-tiled ----
__global__ void k_transpose_bf16(const float* __restrict__ in, ushort_t* __restrict__ out,
                                 int R, int C) {
  __shared__ float ltf[64][65];
  const size_t per = (size_t)R * C;
  const float* src = in + per * blockIdx.z;
  ushort_t* dst = out + per * blockIdx.z;
  int r0 = blockIdx.x * 64, c0 = blockIdx.y * 64;
  int tid = threadIdx.x;
  int cg = (tid & 15) * 4;
  int rr = tid >> 4;
#pragma unroll
  for (int rb = 0; rb < 64; rb += 16) {
    int r = rb + rr;
    float4 v = *(const float4*)(src + (size_t)(r0 + r) * C + c0 + cg);
    ltf[r][cg + 0] = v.x; ltf[r][cg + 1] = v.y;
    ltf[r][cg + 2] = v.z; ltf[r][cg + 3] = v.w;
  }
  __syncthreads();
  int c = tid >> 2, rch = (tid & 3) * 16;
  ushort_t tmp[16];
#pragma unroll
  for (int i = 0; i < 16; ++i) tmp[i] = f2bf(ltf[rch + i][c]);
  ushort_t* dp = dst + (size_t)(c0 + c) * R + r0 + rch;
  *(us8*)dp = *(const us8*)&tmp[0];
  *(us8*)(dp + 8) = *(const us8*)&tmp[8];
}

// ------- router layer1 split-K: p1[kc] = h[:, kc*256:+256] @ gw1 chunk, f64 --
__global__ void k_router1(const float* __restrict__ h, const float* __restrict__ gw1,
                          double* __restrict__ p1) {
  __shared__ float sA[16][65];
  __shared__ float sB[16][65];
  int tx = threadIdx.x, ty = threadIdx.y;
  int tid = ty * 16 + tx;
  int m0 = blockIdx.y * 64, n0 = blockIdx.x * 64;
  int kc = blockIdx.z;
  double acc[4][4] = {};
  for (int k0 = kc * 256; k0 < kc * 256 + 256; k0 += 16) {
    {
      int m = tid & 63, kq = tid >> 6;
      float4 v = *(const float4*)(h + (size_t)(m0 + m) * D_ + k0 + kq * 4);
      sA[kq*4+0][m] = v.x; sA[kq*4+1][m] = v.y; sA[kq*4+2][m] = v.z; sA[kq*4+3][m] = v.w;
    }
    {
      int k = tid >> 4, nq = tid & 15;
      float4 v = *(const float4*)(gw1 + (size_t)(k0 + k) * H1_ + n0 + nq * 4);
      sB[k][nq*4+0] = v.x; sB[k][nq*4+1] = v.y; sB[k][nq*4+2] = v.z; sB[k][nq*4+3] = v.w;
    }
    __syncthreads();
#pragma unroll
    for (int k = 0; k < 16; ++k) {
      float a[4], b[4];
#pragma unroll
      for (int i = 0; i < 4; ++i) a[i] = sA[k][ty + i * 16];
#pragma unroll
      for (int j = 0; j < 4; ++j) b[j] = sB[k][tx * 4 + j];
#pragma unroll
      for (int i = 0; i < 4; ++i)
#pragma unroll
        for (int j = 0; j < 4; ++j)
          acc[i][j] += (double)a[i] * (double)b[j];
    }
    __syncthreads();
  }
  double* pd = p1 + (size_t)kc * T_ * H1_;
  for (int i = 0; i < 4; ++i)
    for (int j = 0; j < 4; ++j) {
      int m = m0 + ty + i * 16, n = n0 + tx * 4 + j;
      pd[(size_t)m * H1_ + n] = acc[i][j];
    }
}

// -------- router: reduce p1 + layers 2+3 + top-2 + counts (wave per token) ---
__global__ void k_router23(const double* __restrict__ p1, const float* __restrict__ gb1,
                           const float* __restrict__ gw2, const float* __restrict__ gb2,
                           const float* __restrict__ gw3,
                           float* __restrict__ logits_out, int* __restrict__ tokExp,
                           float* __restrict__ tokW, int* __restrict__ counts) {
  __shared__ double sG1[4][256];
  __shared__ double sG2[4][64];
  __shared__ double sL[4][8];
  int lane = threadIdx.x & 63, wv = threadIdx.x >> 6;
  int t = blockIdx.x * 4 + wv;
  const size_t TH = (size_t)T_ * H1_;
  const double* gp = p1 + (size_t)t * H1_ + lane * 4;
  double s0 = 0, s1 = 0, s2 = 0, s3 = 0;
#pragma unroll
  for (int kc = 0; kc < 4; ++kc) {
    double2 va = *(const double2*)(gp + kc * TH);
    double2 vb = *(const double2*)(gp + kc * TH + 2);
    s0 += va.x; s1 += va.y; s2 += vb.x; s3 += vb.y;
  }
  int hbase = lane * 4;
  s0 += (double)gb1[hbase + 0]; s1 += (double)gb1[hbase + 1];
  s2 += (double)gb1[hbase + 2]; s3 += (double)gb1[hbase + 3];
  sG1[wv][hbase + 0] = s0 > 0.0 ? s0 : 0.0;
  sG1[wv][hbase + 1] = s1 > 0.0 ? s1 : 0.0;
  sG1[wv][hbase + 2] = s2 > 0.0 ? s2 : 0.0;
  sG1[wv][hbase + 3] = s3 > 0.0 ? s3 : 0.0;
  __syncthreads();
  double acc = (double)gb2[lane];
  for (int k = 0; k < H1_; ++k)
    acc += sG1[wv][k] * (double)gw2[k * H2_ + lane];
  sG2[wv][lane] = acc > 0.0 ? acc : 0.0;
  __syncthreads();
  if (lane < 8) {
    double l = 0.0;
    for (int j = 0; j < H2_; ++j) l += sG2[wv][j] * (double)gw3[j * E_ + lane];
    sL[wv][lane] = l;
    logits_out[(size_t)t * E_ + lane] = (float)l;
  }
  __syncthreads();
  if (lane == 0) {
    double best = -1e300, second = -1e300; int bi = 0, si = 0;
    for (int e = 0; e < E_; ++e) {
      double l = sL[wv][e];
      if (l > best)        { second = best; si = bi; best = l; bi = e; }
      else if (l > second) { second = l; si = e; }
    }
    double w0 = 1.0 / (1.0 + exp(second - best));
    tokExp[t*2]   = bi; tokExp[t*2+1] = si;
    tokW[t*2]     = (float)w0;
    tokW[t*2+1]   = (float)(1.0 - w0);
    atomicAdd(&counts[bi], 1);
    atomicAdd(&counts[si], 1);
  }
}

// ---- assign rows + build 256-row m-tile table (tileE, tileRow, tileCnt) -----
__global__ void k_assign(const int* __restrict__ tokExp, const int* __restrict__ counts,
                         int* cursor, int* __restrict__ list, int* __restrict__ rowOf,
                         int* __restrict__ tileTab) {
  int offs[E_];
  int s = 0;
#pragma unroll
  for (int e = 0; e < E_; ++e) { offs[e] = s; s += counts[e]; }
  if (blockIdx.x == 0 && threadIdx.x == 0) {
    int nt = 0;
    for (int e = 0; e < E_; ++e) {
      int cnt = counts[e];
      for (int m = 0; m * 256 < cnt; ++m) {
        tileTab[nt*3+0] = e;
        tileTab[nt*3+1] = offs[e] + m * 256;
        tileTab[nt*3+2] = (cnt - m * 256) < 256 ? (cnt - m * 256) : 256;
        ++nt;
      }
    }
    for (; nt < NT2_; ++nt) tileTab[nt*3+0] = -1;
  }
  int t = blockIdx.x * 256 + threadIdx.x;
  for (int k = 0; k < 2; ++k) {
    int e = tokExp[t*2+k];
    int pos = atomicAdd(&cursor[e], 1);
    int row = offs[e] + pos;
    list[row] = t;
    rowOf[t*2+k] = row;
  }
}

// -------- grouped GEMM pass1 (persistent): act = gelu(gather(h) @ w1t^T + b1)
// 256x128 tile, BK=64, 3-buffer ring (144 KB LDS), depth-2 prefetch (~600 cyc
// -> covers L3 staging latency), one barrier per K-step, counted WAITVM(6).
// 1056 items on 256 blocks -> makespan 1.21x ideal (was 1.45x at n=256).
__global__ __launch_bounds__(512, 1) void k_moe_ffn1(
    const ushort_t* __restrict__ hb, const ushort_t* __restrict__ w1t,
    const float* __restrict__ b1, ushort_t* __restrict__ act,
    const int* __restrict__ list, const int* __restrict__ tileTab, int* q) {
  __shared__ short8 lA[3][2][16][64];   // 96 KB: [buf][ks][rowfrag][lane]
  __shared__ short8 lB[3][2][8][64];    // 48 KB
  __shared__ int sIdx;
  int tid = threadIdx.x, w = tid >> 6, lane = tid & 63;
  int m16 = lane & 15, kq = lane >> 4;
  int wr = w >> 1, wc = w & 1;          // 4M x 2N
  int quad = lane >> 4, cn = lane & 15;
  for (;;) {
    __syncthreads();                    // all waves done with prev item's LDS
    if (tid == 0) sIdx = atomicAdd(q, 1);
    __syncthreads();
    int idx = sIdx;
    if (idx >= NT2_ * 32) return;
    int ti = idx >> 5, nb = idx & 31;   // 32 n-tiles of 128
    int e = tileTab[ti*3+0];
    if (e < 0) continue;
    int rowStart = tileTab[ti*3+1];
    int cntTile  = tileTab[ti*3+2];
    int nBase = nb * 128;
    const ushort_t* B = w1t + (size_t)e * F_ * D_;
    int gr0 = rowStart + w * 32 + m16;
    int gr1 = gr0 + 16;
    int t0 = list[min(gr0, NROW_ - 1)];
    int t1 = list[min(gr1, NROW_ - 1)];
    const ushort_t* aS0 = hb + (size_t)t0 * D_ + kq * 8;
    const ushort_t* aS1 = hb + (size_t)t1 * D_ + kq * 8;
    const ushort_t* bS0 = B + (size_t)(nBase + w * 16 + m16) * D_ + kq * 8;
    f32x4 acc[4][4] = {};
    short8 (*A0)[16][64] = lA[0], (*A1)[16][64] = lA[1], (*A2)[16][64] = lA[2];
    short8 (*B0)[8][64] = lB[0], (*B1)[8][64] = lB[1], (*B2)[8][64] = lB[2];
    stage6(aS0, aS1, bS0, A0, B0, w);                 // tile 0
    stage6(aS0 + 64, aS1 + 64, bS0 + 64, A1, B1, w);  // tile 1
    const int NSTEP = D_ / 64;   // 16
    for (int t = 0; t < NSTEP - 2; ++t) {
      WAITVM(6);                 // tile t landed (this wave); t+1 in flight
      BARRIER();                 // all waves: tile t ready; buf(t-1) free
      int k0 = (t + 2) * 64;
      stage6(aS0 + k0, aS1 + k0, bS0 + k0, A2, B2, w);  // tile t+2
      mfma_step32(A0, B0, wr, wc, lane, acc);
      short8 (*ta)[16][64] = A0; A0 = A1; A1 = A2; A2 = ta;
      short8 (*tb)[8][64]  = B0; B0 = B1; B1 = B2; B2 = tb;
    }
    WAITVM(6); BARRIER(); mfma_step32(A0, B0, wr, wc, lane, acc);  // NSTEP-2
    WAITVM(0); BARRIER(); mfma_step32(A1, B1, wr, wc, lane, acc);  // NSTEP-1
    const float* b1e = b1 + (size_t)e * F_;
    float bj[4];
#pragma unroll
    for (int j = 0; j < 4; ++j) bj[j] = b1e[nBase + wc * 64 + j * 16 + cn];
#pragma unroll
    for (int i = 0; i < 4; ++i) {
      int lrow = wr * 64 + i * 16 + quad * 4;
#pragma unroll
      for (int r = 0; r < 4; ++r) {
        if (lrow + r < cntTile) {
          size_t gr = (size_t)rowStart + lrow + r;
#pragma unroll
          for (int j = 0; j < 4; ++j) {
            int n = nBase + wc * 64 + j * 16 + cn;
            float x = acc[i][j][r] + bj[j];
            act[gr * F_ + n] = f2bf(gelu_tanh(x));
          }
        }
      }
    }
  }
}

// -------- grouped GEMM pass2 (persistent, split-K=KC): partial = act @ w2t^T -
__global__ __launch_bounds__(512, 1) void k_moe_ffn2(
    const ushort_t* __restrict__ act, const ushort_t* __restrict__ w2t,
    float* __restrict__ part, const int* __restrict__ tileTab, int* q, int KC) {
  __shared__ short8 lA[3][2][16][64];
  __shared__ short8 lB[3][2][8][64];
  __shared__ int sIdx;
  int tid = threadIdx.x, w = tid >> 6, lane = tid & 63;
  int m16 = lane & 15, kq = lane >> 4;
  int wr = w >> 1, wc = w & 1;
  int quad = lane >> 4, cn = lane & 15;
  const int ipt = 8 * KC;            // items per m-tile: 8 n-tiles(128) x KC
  const int kcs = F_ / KC;           // K per slice
  const int NSTEP = kcs / 64;
  for (;;) {
    __syncthreads();
    if (tid == 0) sIdx = atomicAdd(q, 1);
    __syncthreads();
    int idx = sIdx;
    if (idx >= NT2_ * ipt) return;
    int ti = idx / ipt, sub = idx - ti * ipt;
    int nb = sub / KC, kc = sub - nb * KC;
    int e = tileTab[ti*3+0];
    if (e < 0) continue;
    int rowStart = tileTab[ti*3+1];
    int cntTile  = tileTab[ti*3+2];
    int nBase = nb * 128;
    int kBase = kc * kcs;
    const ushort_t* Bw = w2t + (size_t)e * D_ * F_;
    int gr0 = rowStart + w * 32 + m16;
    int gr1 = gr0 + 16;
    const ushort_t* aS0 = act + (size_t)min(gr0, NROW_ - 1) * F_ + kBase + kq * 8;
    const ushort_t* aS1 = act + (size_t)min(gr1, NROW_ - 1) * F_ + kBase + kq * 8;
    const ushort_t* bS0 = Bw + (size_t)(nBase + w * 16 + m16) * F_ + kBase + kq * 8;
    f32x4 acc[4][4] = {};
    short8 (*A0)[16][64] = lA[0], (*A1)[16][64] = lA[1], (*A2)[16][64] = lA[2];
    short8 (*B0)[8][64] = lB[0], (*B1)[8][64] = lB[1], (*B2)[8][64] = lB[2];
    stage6(aS0, aS1, bS0, A0, B0, w);
    stage6(aS0 + 64, aS1 + 64, bS0 + 64, A1, B1, w);
    for (int t = 0; t < NSTEP - 2; ++t) {
      WAITVM(6);
      BARRIER();
      int k0 = (t + 2) * 64;
      stage6(aS0 + k0, aS1 + k0, bS0 + k0, A2, B2, w);
      mfma_step32(A0, B0, wr, wc, lane, acc);
      short8 (*ta)[16][64] = A0; A0 = A1; A1 = A2; A2 = ta;
      short8 (*tb)[8][64]  = B0; B0 = B1; B1 = B2; B2 = tb;
    }
    WAITVM(6); BARRIER(); mfma_step32(A0, B0, wr, wc, lane, acc);
    WAITVM(0); BARRIER(); mfma_step32(A1, B1, wr, wc, lane, acc);
    float* pd = part + (size_t)kc * NROW_ * D_;
#pragma unroll
    for (int i = 0; i < 4; ++i) {
      int lrow = wr * 64 + i * 16 + quad * 4;
#pragma unroll
      for (int r = 0; r < 4; ++r) {
        if (lrow + r < cntTile) {
          size_t gr = (size_t)rowStart + lrow + r;
#pragma unroll
          for (int j = 0; j < 4; ++j) {
            int n = nBase + wc * 64 + j * 16 + cn;
            pd[gr * D_ + n] = acc[i][j][r];
          }
        }
      }
    }
  }
}

// -- combine: out[t] = sum_k tokW[t,k]*(sum_kc part[kc][row_k] + b2[e_k]) -----
__global__ void k_combine(const float* __restrict__ part, const int* __restrict__ rowOf,
                          const int* __restrict__ tokExp, const float* __restrict__ tokW,
                          const float* __restrict__ b2, float* __restrict__ out, int KC) {
  int t = blockIdx.x;
  int rA = rowOf[t*2], rB = rowOf[t*2+1];
  int eA = tokExp[t*2], eB = tokExp[t*2+1];
  float wA = tokW[t*2] * SCALE_, wB = tokW[t*2+1] * SCALE_;
  int d = threadIdx.x * 4;
  const size_t P = (size_t)NROW_ * D_;
  float sax = 0, say = 0, saz = 0, saw = 0;
  float sbx = 0, sby = 0, sbz = 0, sbw = 0;
  for (int k = 0; k < KC; ++k) {
    float4 a = *(const float4*)(part + (size_t)k * P + (size_t)rA * D_ + d);
    float4 b = *(const float4*)(part + (size_t)k * P + (size_t)rB * D_ + d);
    sax += a.x; say += a.y; saz += a.z; saw += a.w;
    sbx += b.x; sby += b.y; sbz += b.z; sbw += b.w;
  }
  float4 ba = *(const float4*)(b2 + (size_t)eA * D_ + d);
  float4 bb = *(const float4*)(b2 + (size_t)eB * D_ + d);
  float4 o;
  o.x = wA * (sax + ba.x) + wB * (sbx + bb.x);
  o.y = wA * (say + ba.y) + wB * (sby + bb.y);
  o.z = wA * (saz + ba.z) + wB * (sbz + bb.z);
  o.w = wA * (saw + ba.w) + wB * (sbw + bb.w);
  *(float4*)(out + (size_t)t * D_ + d) = o;
}

extern "C" void kernel_launch(void* const* d_in, const int* in_sizes, int n_in,
                              void* d_out, int out_size, void* d_ws, size_t ws_size,
                              hipStream_t stream) {
  const float* h   = (const float*)d_in[0];
  const float* gw1 = (const float*)d_in[1];
  const float* gb1 = (const float*)d_in[2];
  const float* gw2 = (const float*)d_in[3];
  const float* gb2 = (const float*)d_in[4];
  const float* gw3 = (const float*)d_in[5];
  const float* w1  = (const float*)d_in[6];
  const float* b1  = (const float*)d_in[7];
  const float* w2  = (const float*)d_in[8];
  const float* b2  = (const float*)d_in[9];
  float* out    = (float*)d_out;
  float* logits = out + (size_t)T_ * D_;

  char* ws = (char*)d_ws;
  size_t o = 0;
  auto alloc = [&](size_t bytes) -> void* {
    o = (o + 255) & ~(size_t)255;
    void* p = ws + o;
    o += bytes;
    return p;
  };
  int*      counts  = (int*)alloc((2 * E_ + 2) * 4);  // counts[8]+cursor[8]+q[2]
  int*      cursor  = counts + E_;
  int*      qq      = counts + 2 * E_;
  int*      tileTab = (int*)alloc((size_t)NT2_ * 3 * 4);
  int*      tokExp  = (int*)alloc((size_t)T_ * 2 * 4);
  float*    tokW    = (float*)alloc((size_t)T_ * 2 * 4);
  int*      list    = (int*)alloc((size_t)NROW_ * 4);
  int*      rowOf   = (int*)alloc((size_t)NROW_ * 4);
  ushort_t* hb      = (ushort_t*)alloc((size_t)T_ * D_ * 2);
  ushort_t* w2t     = (ushort_t*)alloc((size_t)E_ * D_ * F_ * 2);
  // act (64 MB) aliases p1 (32 MB; dead after k_router23)
  char*     bigA    = (char*)alloc((size_t)NROW_ * F_ * 2);
  double*   p1      = (double*)bigA;
  ushort_t* act     = (ushort_t*)bigA;
  // bigB: w1t (64 MB; dead after ffn1) aliases part (KC x 32 MB f32).
  // KC=4 needs 128 MB -> guard on ws_size, else fall back to KC=2 (64 MB).
  size_t oAligned = (o + 255) & ~(size_t)255;
  size_t w1tBytes = (size_t)E_ * D_ * F_ * 2;                  // 64 MB
  int KC = (ws_size >= oAligned + (size_t)4 * NROW_ * D_ * 4) ? 4 : 2;
  size_t partBytes = (size_t)KC * NROW_ * D_ * 4;
  char*     bigB    = (char*)alloc(partBytes > w1tBytes ? partBytes : w1tBytes);
  ushort_t* w1t     = (ushort_t*)bigB;
  float*    part    = (float*)bigB;
  (void)in_sizes; (void)n_in; (void)out_size;

  hipMemsetAsync(counts, 0, (2 * E_ + 2) * 4, stream);
  k_cvt_h<<<T_ * D_ / 2048, 256, 0, stream>>>(h, hb);
  k_transpose_bf16<<<dim3(D_ / 64, F_ / 64, E_), 256, 0, stream>>>(w1, w1t, D_, F_);
  k_transpose_bf16<<<dim3(F_ / 64, D_ / 64, E_), 256, 0, stream>>>(w2, w2t, F_, D_);
  k_router1<<<dim3(H1_ / 64, T_ / 64, 4), dim3(16, 16), 0, stream>>>(h, gw1, p1);
  k_router23<<<T_ / 4, 256, 0, stream>>>(p1, gb1, gw2, gb2, gw3, logits, tokExp, tokW, counts);
  k_assign<<<T_ / 256, 256, 0, stream>>>(tokExp, counts, cursor, list, rowOf, tileTab);
  k_moe_ffn1<<<256, 512, 0, stream>>>(hb, w1t, b1, act, list, tileTab, qq + 0);
  k_moe_ffn2<<<256, 512, 0, stream>>>(act, w2t, part, tileTab, qq + 1, KC);
  k_combine<<<T_, 256, 0, stream>>>(part, rowOf, tokExp, tokW, b2, out, KC);
}

// Round 14
// 836.745 us; speedup vs baseline: 1.1528x; 1.1528x over previous
//
#include <hip/hip_runtime.h>
#include <stdint.h>

#define T_  4096
#define D_  1024
#define E_  8
#define F_  4096
#define H1_ 256
#define H2_ 64
#define SCALE_ 1.0f
#define NROW_ (2 * T_)
#define NTILES_ 72   // max active 128-row m-tiles: 8192/128 + (E-1) = 71

typedef unsigned short ushort_t;
typedef unsigned int   uint32;
typedef __attribute__((ext_vector_type(8))) short  short8;
typedef __attribute__((ext_vector_type(4))) float  f32x4;
typedef __attribute__((ext_vector_type(8))) unsigned short us8;

// raw barrier: no compiler-inserted vmcnt(0) drain
#define BARRIER() do { asm volatile("" ::: "memory"); __builtin_amdgcn_s_barrier(); asm volatile("" ::: "memory"); } while (0)
#define WAITVM(N) asm volatile("s_waitcnt vmcnt(" #N ")" ::: "memory")

__device__ __forceinline__ ushort_t f2bf(float f) {
  uint32 u = __float_as_uint(f);
  u += 0x7FFFu + ((u >> 16) & 1u);   // RNE
  return (ushort_t)(u >> 16);
}
// jax.nn.gelu default = tanh approximation
__device__ __forceinline__ float gelu_tanh(float x) {
  float u = 0.7978845608028654f * (x + 0.044715f * x * x * x);
  float e = __expf(2.0f * u);
  return 0.5f * x * (1.0f + (1.0f - 2.0f / (e + 1.0f)));
}
__device__ __forceinline__ void gll16(const void* gptr, void* lptr) {
  void* g = const_cast<void*>(gptr);
  __builtin_amdgcn_global_load_lds((__attribute__((address_space(1))) void*)g,
                                   (__attribute__((address_space(3))) void*)lptr,
                                   16, 0, 0);
}

// stage one 128x32 A-tile half + B-tile half for this wave into LDS buffer
__device__ __forceinline__ void stage4(const ushort_t* a0, const ushort_t* a1,
                                       const ushort_t* b0, const ushort_t* b1,
                                       short8* An, short8* Bn, int w) {
  gll16(a0, An + (w * 2 + 0) * 64);
  gll16(a1, An + (w * 2 + 1) * 64);
  gll16(b0, Bn + (w * 2 + 0) * 64);
  gll16(b1, Bn + (w * 2 + 1) * 64);
}

__device__ __forceinline__ void mfma_step(const short8* Ac, const short8* Bc,
                                          int wr, int wc, int lane, f32x4 acc[4][4]) {
  short8 af[4], bf4[4];
#pragma unroll
  for (int i = 0; i < 4; ++i) af[i] = Ac[(wr * 4 + i) * 64 + lane];
#pragma unroll
  for (int j = 0; j < 4; ++j) bf4[j] = Bc[(wc * 4 + j) * 64 + lane];
#pragma unroll
  for (int i = 0; i < 4; ++i)
#pragma unroll
    for (int j = 0; j < 4; ++j)
      acc[i][j] = __builtin_amdgcn_mfma_f32_16x16x32_bf16(af[i], bf4[j], acc[i][j], 0, 0, 0);
}

// ===== fused preprocessing: router1 + cvt_h + transpose(w1) + transpose(w2) ==
// block ranges: [0,1024) router1 | [1024,3072) cvt_h | [3072,11264) w1t
//               | [11264,19456) w2t.  One launch: kills 3 kernel boundaries and
//               makes the prep bucket visible as a single dispatch in rocprof.
#define PB_R1 1024
#define PB_CV 2048
#define PB_T1 8192
#define PB_T2 8192

__device__ __forceinline__ void prep_transpose(const float* __restrict__ in,
                                               ushort_t* __restrict__ out,
                                               int R, int C, int bxx, int by, int bz,
                                               float (*ltf)[65]) {
  const size_t per = (size_t)R * C;
  const float* src = in + per * bz;
  ushort_t* dst = out + per * bz;
  int r0 = bxx * 64, c0 = by * 64;
  int tid = threadIdx.x;
  int cg = (tid & 15) * 4;
  int rr = tid >> 4;
#pragma unroll
  for (int rb = 0; rb < 64; rb += 16) {
    int r = rb + rr;
    float4 v = *(const float4*)(src + (size_t)(r0 + r) * C + c0 + cg);
    ltf[r][cg + 0] = v.x; ltf[r][cg + 1] = v.y;
    ltf[r][cg + 2] = v.z; ltf[r][cg + 3] = v.w;
  }
  __syncthreads();
  int c = tid >> 2, rch = (tid & 3) * 16;
  ushort_t tmp[16];
#pragma unroll
  for (int i = 0; i < 16; ++i) tmp[i] = f2bf(ltf[rch + i][c]);
  ushort_t* dp = dst + (size_t)(c0 + c) * R + r0 + rch;
  *(us8*)dp = *(const us8*)&tmp[0];
  *(us8*)(dp + 8) = *(const us8*)&tmp[8];
}

__global__ __launch_bounds__(256) void k_prep(
    const float* __restrict__ h, ushort_t* __restrict__ hb,
    const float* __restrict__ w1, ushort_t* __restrict__ w1t,
    const float* __restrict__ w2, ushort_t* __restrict__ w2t,
    const float* __restrict__ gw1, double* __restrict__ p1) {
  __shared__ char smem[64 * 65 * 4];          // 16.6 KB, unioned across branches
  int b = blockIdx.x;
  int tid = threadIdx.x;
  if (b < PB_R1) {
    // ---- router layer1 split-K (f64 accum), flat-256 re-index of 16x16 ----
    float (*sA)[65] = (float(*)[65])smem;                    // [16][65]
    float (*sB)[65] = (float(*)[65])(smem + 16 * 65 * 4);    // [16][65]
    int tx = tid & 15, ty = tid >> 4;
    int kc = b >> 8, rem = b & 255;
    int by = rem >> 2, bx = rem & 3;
    int m0 = by * 64, n0 = bx * 64;
    double acc[4][4] = {};
    for (int k0 = kc * 256; k0 < kc * 256 + 256; k0 += 16) {
      {
        int m = tid & 63, kq = tid >> 6;
        float4 v = *(const float4*)(h + (size_t)(m0 + m) * D_ + k0 + kq * 4);
        sA[kq*4+0][m] = v.x; sA[kq*4+1][m] = v.y; sA[kq*4+2][m] = v.z; sA[kq*4+3][m] = v.w;
      }
      {
        int k = tid >> 4, nq = tid & 15;
        float4 v = *(const float4*)(gw1 + (size_t)(k0 + k) * H1_ + n0 + nq * 4);
        sB[k][nq*4+0] = v.x; sB[k][nq*4+1] = v.y; sB[k][nq*4+2] = v.z; sB[k][nq*4+3] = v.w;
      }
      __syncthreads();
#pragma unroll
      for (int k = 0; k < 16; ++k) {
        float a[4], bb[4];
#pragma unroll
        for (int i = 0; i < 4; ++i) a[i] = sA[k][ty + i * 16];
#pragma unroll
        for (int j = 0; j < 4; ++j) bb[j] = sB[k][tx * 4 + j];
#pragma unroll
        for (int i = 0; i < 4; ++i)
#pragma unroll
          for (int j = 0; j < 4; ++j)
            acc[i][j] += (double)a[i] * (double)bb[j];
      }
      __syncthreads();
    }
    double* pd = p1 + (size_t)kc * T_ * H1_;
    for (int i = 0; i < 4; ++i)
      for (int j = 0; j < 4; ++j) {
        int m = m0 + ty + i * 16, n = n0 + tx * 4 + j;
        pd[(size_t)m * H1_ + n] = acc[i][j];
      }
    return;
  }
  b -= PB_R1;
  if (b < PB_CV) {
    // ---------------- h -> bf16 ----------------
    int i = (b * 256 + tid) * 8;
    float4 a = *(const float4*)(h + i);
    float4 c = *(const float4*)(h + i + 4);
    short8 v;
    v[0] = (short)f2bf(a.x); v[1] = (short)f2bf(a.y);
    v[2] = (short)f2bf(a.z); v[3] = (short)f2bf(a.w);
    v[4] = (short)f2bf(c.x); v[5] = (short)f2bf(c.y);
    v[6] = (short)f2bf(c.z); v[7] = (short)f2bf(c.w);
    *(short8*)(hb + i) = v;
    return;
  }
  b -= PB_CV;
  float (*ltf)[65] = (float(*)[65])smem;
  if (b < PB_T1) {
    // w1 [E][D][F] -> w1t [E][F][D]; original grid (16, 64, 8)
    int bz = b >> 10, rem = b & 1023;
    int by = rem >> 4, bxx = rem & 15;
    prep_transpose(w1, w1t, D_, F_, bxx, by, bz, ltf);
    return;
  }
  b -= PB_T1;
  {
    // w2 [E][F][D] -> w2t [E][D][F]; original grid (64, 16, 8)
    int bz = b >> 10, rem = b & 1023;
    int by = rem >> 6, bxx = rem & 63;
    prep_transpose(w2, w2t, F_, D_, bxx, by, bz, ltf);
  }
}

// -------- router: reduce p1 + layers 2+3 + top-2 + counts (wave per token) ---
__global__ void k_router23(const double* __restrict__ p1, const float* __restrict__ gb1,
                           const float* __restrict__ gw2, const float* __restrict__ gb2,
                           const float* __restrict__ gw3,
                           float* __restrict__ logits_out, int* __restrict__ tokExp,
                           float* __restrict__ tokW, int* __restrict__ counts) {
  __shared__ double sG1[4][256];
  __shared__ double sG2[4][64];
  __shared__ double sL[4][8];
  int lane = threadIdx.x & 63, wv = threadIdx.x >> 6;
  int t = blockIdx.x * 4 + wv;
  const size_t TH = (size_t)T_ * H1_;
  const double* gp = p1 + (size_t)t * H1_ + lane * 4;
  double s0 = 0, s1 = 0, s2 = 0, s3 = 0;
#pragma unroll
  for (int kc = 0; kc < 4; ++kc) {
    double2 va = *(const double2*)(gp + kc * TH);
    double2 vb = *(const double2*)(gp + kc * TH + 2);
    s0 += va.x; s1 += va.y; s2 += vb.x; s3 += vb.y;
  }
  int hbase = lane * 4;
  s0 += (double)gb1[hbase + 0]; s1 += (double)gb1[hbase + 1];
  s2 += (double)gb1[hbase + 2]; s3 += (double)gb1[hbase + 3];
  sG1[wv][hbase + 0] = s0 > 0.0 ? s0 : 0.0;
  sG1[wv][hbase + 1] = s1 > 0.0 ? s1 : 0.0;
  sG1[wv][hbase + 2] = s2 > 0.0 ? s2 : 0.0;
  sG1[wv][hbase + 3] = s3 > 0.0 ? s3 : 0.0;
  __syncthreads();
  double acc = (double)gb2[lane];
  for (int k = 0; k < H1_; ++k)
    acc += sG1[wv][k] * (double)gw2[k * H2_ + lane];
  sG2[wv][lane] = acc > 0.0 ? acc : 0.0;
  __syncthreads();
  if (lane < 8) {
    double l = 0.0;
    for (int j = 0; j < H2_; ++j) l += sG2[wv][j] * (double)gw3[j * E_ + lane];
    sL[wv][lane] = l;
    logits_out[(size_t)t * E_ + lane] = (float)l;
  }
  __syncthreads();
  if (lane == 0) {
    double best = -1e300, second = -1e300; int bi = 0, si = 0;
    for (int e = 0; e < E_; ++e) {
      double l = sL[wv][e];
      if (l > best)        { second = best; si = bi; best = l; bi = e; }
      else if (l > second) { second = l; si = e; }
    }
    double w0 = 1.0 / (1.0 + exp(second - best));
    tokExp[t*2]   = bi; tokExp[t*2+1] = si;
    tokW[t*2]     = (float)w0;
    tokW[t*2+1]   = (float)(1.0 - w0);
    atomicAdd(&counts[bi], 1);
    atomicAdd(&counts[si], 1);
  }
}

// ---- assign rows + build 128-row m-tile table (tileE, tileRow, tileCnt) -----
__global__ void k_assign(const int* __restrict__ tokExp, const int* __restrict__ counts,
                         int* cursor, int* __restrict__ list, int* __restrict__ rowOf,
                         int* __restrict__ tileTab) {
  int offs[E_];
  int s = 0;
#pragma unroll
  for (int e = 0; e < E_; ++e) { offs[e] = s; s += counts[e]; }
  if (blockIdx.x == 0 && threadIdx.x == 0) {
    int nt = 0;
    for (int e = 0; e < E_; ++e) {
      int cnt = counts[e];
      for (int m = 0; m * 128 < cnt; ++m) {
        tileTab[nt*3+0] = e;
        tileTab[nt*3+1] = offs[e] + m * 128;
        tileTab[nt*3+2] = (cnt - m * 128) < 128 ? (cnt - m * 128) : 128;
        ++nt;
      }
    }
    for (; nt < NTILES_; ++nt) tileTab[nt*3+0] = -1;
  }
  int t = blockIdx.x * 256 + threadIdx.x;
  for (int k = 0; k < 2; ++k) {
    int e = tokExp[t*2+k];
    int pos = atomicAdd(&cursor[e], 1);
    int row = offs[e] + pos;
    list[row] = t;
    rowOf[t*2+k] = row;
  }
}

// -------- grouped GEMM pass1: act = gelu(gather(h) @ w1t^T + b1) -------------
// ROUND-2 CONFIG (best measured): 128x128 tile, BK=32, 2-buffer, WAITVM(4),
// static grid. 256x/3-buf/phase-split variants all measured worse (r3-r12).
__global__ __launch_bounds__(256) void k_moe_ffn1(
    const ushort_t* __restrict__ hb, const ushort_t* __restrict__ w1t,
    const float* __restrict__ b1, ushort_t* __restrict__ act,
    const int* __restrict__ list, const int* __restrict__ tileTab) {
  int ti = blockIdx.y;
  int e = tileTab[ti*3+0];
  if (e < 0) return;
  int rowStart = tileTab[ti*3+1];
  int cntTile  = tileTab[ti*3+2];
  int nBase = blockIdx.x * 128;
  const ushort_t* B = w1t + (size_t)e * F_ * D_;
  int tid = threadIdx.x, w = tid >> 6, lane = tid & 63;
  int m16 = lane & 15, kq = lane >> 4;
  __shared__ short8 lA[2][512];
  __shared__ short8 lB[2][512];
  int gr0 = rowStart + (w * 2) * 16 + m16;
  int gr1 = gr0 + 16;
  int t0 = list[min(gr0, NROW_ - 1)];
  int t1 = list[min(gr1, NROW_ - 1)];
  const ushort_t* aS0 = hb + (size_t)t0 * D_ + kq * 8;
  const ushort_t* aS1 = hb + (size_t)t1 * D_ + kq * 8;
  const ushort_t* bS0 = B + (size_t)(nBase + (w * 2) * 16 + m16) * D_ + kq * 8;
  const ushort_t* bS1 = bS0 + (size_t)16 * D_;
  int wr = w >> 1, wc = w & 1;
  f32x4 acc[4][4] = {};
  short8* Ac = lA[0]; short8* An = lA[1];
  short8* Bc = lB[0]; short8* Bn = lB[1];
  stage4(aS0, aS1, bS0, bS1, Ac, Bc, w);            // k=0
  const int NSTEP = D_ / 32;
  for (int step = 0; step < NSTEP - 1; ++step) {
    int k0 = (step + 1) * 32;
    stage4(aS0 + k0, aS1 + k0, bS0 + k0, bS1 + k0, An, Bn, w);  // prefetch next
    WAITVM(4);        // current tile's 4 loads landed; prefetch stays in flight
    BARRIER();
    mfma_step(Ac, Bc, wr, wc, lane, acc);
    BARRIER();        // all waves done reading cur before it is restaged
    short8* t;
    t = Ac; Ac = An; An = t;
    t = Bc; Bc = Bn; Bn = t;
  }
  WAITVM(0);
  BARRIER();
  mfma_step(Ac, Bc, wr, wc, lane, acc);
  const float* b1e = b1 + (size_t)e * F_;
  int quad = lane >> 4, cn = lane & 15;
#pragma unroll
  for (int i = 0; i < 4; ++i) {
    int lrow = (wr * 4 + i) * 16 + quad * 4;
#pragma unroll
    for (int r = 0; r < 4; ++r) {
      if (lrow + r < cntTile) {
        size_t gr = (size_t)rowStart + lrow + r;
#pragma unroll
        for (int j = 0; j < 4; ++j) {
          int n = nBase + (wc * 4 + j) * 16 + cn;
          float x = acc[i][j][r] + b1e[n];
          act[gr * F_ + n] = f2bf(gelu_tanh(x));
        }
      }
    }
  }
}

// -------- grouped GEMM pass2 split-K=2: partial[kc] = act @ w2t^T ------------
__global__ __launch_bounds__(256) void k_moe_ffn2(
    const ushort_t* __restrict__ act, const ushort_t* __restrict__ w2t,
    float* __restrict__ part, const int* __restrict__ tileTab) {
  int ti = blockIdx.y;
  int e = tileTab[ti*3+0];
  if (e < 0) return;
  int rowStart = tileTab[ti*3+1];
  int cntTile  = tileTab[ti*3+2];
  int kc = blockIdx.z;
  int nBase = blockIdx.x * 128;
  const ushort_t* Bw = w2t + (size_t)e * D_ * F_;
  int tid = threadIdx.x, w = tid >> 6, lane = tid & 63;
  int m16 = lane & 15, kq = lane >> 4;
  __shared__ short8 lA[2][512];
  __shared__ short8 lB[2][512];
  int gr0 = rowStart + (w * 2) * 16 + m16;
  int gr1 = gr0 + 16;
  int kBase = kc * (F_ / 2);
  const ushort_t* aS0 = act + (size_t)min(gr0, NROW_ - 1) * F_ + kBase + kq * 8;
  const ushort_t* aS1 = act + (size_t)min(gr1, NROW_ - 1) * F_ + kBase + kq * 8;
  const ushort_t* bS0 = Bw + (size_t)(nBase + (w * 2) * 16 + m16) * F_ + kBase + kq * 8;
  const ushort_t* bS1 = bS0 + (size_t)16 * F_;
  int wr = w >> 1, wc = w & 1;
  f32x4 acc[4][4] = {};
  short8* Ac = lA[0]; short8* An = lA[1];
  short8* Bc = lB[0]; short8* Bn = lB[1];
  stage4(aS0, aS1, bS0, bS1, Ac, Bc, w);            // k=kBase
  const int NSTEP = (F_ / 2) / 32;
  for (int step = 0; step < NSTEP - 1; ++step) {
    int k0 = (step + 1) * 32;
    stage4(aS0 + k0, aS1 + k0, bS0 + k0, bS1 + k0, An, Bn, w);  // prefetch next
    WAITVM(4);
    BARRIER();
    mfma_step(Ac, Bc, wr, wc, lane, acc);
    BARRIER();
    short8* t;
    t = Ac; Ac = An; An = t;
    t = Bc; Bc = Bn; Bn = t;
  }
  WAITVM(0);
  BARRIER();
  mfma_step(Ac, Bc, wr, wc, lane, acc);
  float* pd = part + (size_t)kc * NROW_ * D_;
  int quad = lane >> 4, cn = lane & 15;
#pragma unroll
  for (int i = 0; i < 4; ++i) {
    int lrow = (wr * 4 + i) * 16 + quad * 4;
#pragma unroll
    for (int r = 0; r < 4; ++r) {
      if (lrow + r < cntTile) {
        size_t gr = (size_t)rowStart + lrow + r;
#pragma unroll
        for (int j = 0; j < 4; ++j) {
          int n = nBase + (wc * 4 + j) * 16 + cn;
          pd[gr * D_ + n] = acc[i][j][r];
        }
      }
    }
  }
}

// -- combine: out[t] = sum_k tokW[t,k]*(part0[row_k]+part1[row_k]+b2[e_k]) ----
__global__ void k_combine(const float* __restrict__ part, const int* __restrict__ rowOf,
                          const int* __restrict__ tokExp, const float* __restrict__ tokW,
                          const float* __restrict__ b2, float* __restrict__ out) {
  int t = blockIdx.x;
  int rA = rowOf[t*2], rB = rowOf[t*2+1];
  int eA = tokExp[t*2], eB = tokExp[t*2+1];
  float wA = tokW[t*2] * SCALE_, wB = tokW[t*2+1] * SCALE_;
  int d = threadIdx.x * 4;
  const size_t P = (size_t)NROW_ * D_;
  float4 a0 = *(const float4*)(part + (size_t)rA * D_ + d);
  float4 a1 = *(const float4*)(part + P + (size_t)rA * D_ + d);
  float4 b0 = *(const float4*)(part + (size_t)rB * D_ + d);
  float4 b1 = *(const float4*)(part + P + (size_t)rB * D_ + d);
  float4 ba = *(const float4*)(b2 + (size_t)eA * D_ + d);
  float4 bb = *(const float4*)(b2 + (size_t)eB * D_ + d);
  float4 o;
  o.x = wA * (a0.x + a1.x + ba.x) + wB * (b0.x + b1.x + bb.x);
  o.y = wA * (a0.y + a1.y + ba.y) + wB * (b0.y + b1.y + bb.y);
  o.z = wA * (a0.z + a1.z + ba.z) + wB * (b0.z + b1.z + bb.z);
  o.w = wA * (a0.w + a1.w + ba.w) + wB * (b0.w + b1.w + bb.w);
  *(float4*)(out + (size_t)t * D_ + d) = o;
}

extern "C" void kernel_launch(void* const* d_in, const int* in_sizes, int n_in,
                              void* d_out, int out_size, void* d_ws, size_t ws_size,
                              hipStream_t stream) {
  const float* h   = (const float*)d_in[0];
  const float* gw1 = (const float*)d_in[1];
  const float* gb1 = (const float*)d_in[2];
  const float* gw2 = (const float*)d_in[3];
  const float* gb2 = (const float*)d_in[4];
  const float* gw3 = (const float*)d_in[5];
  const float* w1  = (const float*)d_in[6];
  const float* b1  = (const float*)d_in[7];
  const float* w2  = (const float*)d_in[8];
  const float* b2  = (const float*)d_in[9];
  float* out    = (float*)d_out;
  float* logits = out + (size_t)T_ * D_;

  char* ws = (char*)d_ws;
  size_t o = 0;
  auto alloc = [&](size_t bytes) -> void* {
    o = (o + 255) & ~(size_t)255;
    void* p = ws + o;
    o += bytes;
    return p;
  };
  int*      counts  = (int*)alloc(2 * E_ * 4);   // counts[8] + cursor[8], one memset
  int*      cursor  = counts + E_;
  int*      tileTab = (int*)alloc((size_t)NTILES_ * 3 * 4);
  int*      tokExp  = (int*)alloc((size_t)T_ * 2 * 4);
  float*    tokW    = (float*)alloc((size_t)T_ * 2 * 4);
  int*      list    = (int*)alloc((size_t)NROW_ * 4);
  int*      rowOf   = (int*)alloc((size_t)NROW_ * 4);
  ushort_t* hb      = (ushort_t*)alloc((size_t)T_ * D_ * 2);
  ushort_t* w2t     = (ushort_t*)alloc((size_t)E_ * D_ * F_ * 2);
  // act (64 MB) aliases p1 (32 MB; dead after k_router23)
  char*     bigA    = (char*)alloc((size_t)NROW_ * F_ * 2);
  double*   p1      = (double*)bigA;
  ushort_t* act     = (ushort_t*)bigA;
  // partial (2x NROW x D f32 = 64 MB) aliases w1t (64 MB; dead after ffn1)
  char*     bigB    = (char*)alloc((size_t)E_ * D_ * F_ * 2);
  ushort_t* w1t     = (ushort_t*)bigB;
  float*    part    = (float*)bigB;
  (void)ws_size; (void)in_sizes; (void)n_in; (void)out_size;

  hipMemsetAsync(counts, 0, 2 * E_ * 4, stream);
  k_prep<<<PB_R1 + PB_CV + PB_T1 + PB_T2, 256, 0, stream>>>(h, hb, w1, w1t, w2, w2t, gw1, p1);
  k_router23<<<T_ / 4, 256, 0, stream>>>(p1, gb1, gw2, gb2, gw3, logits, tokExp, tokW, counts);
  k_assign<<<T_ / 256, 256, 0, stream>>>(tokExp, counts, cursor, list, rowOf, tileTab);
  k_moe_ffn1<<<dim3(F_ / 128, NTILES_), 256, 0, stream>>>(hb, w1t, b1, act, list, tileTab);
  k_moe_ffn2<<<dim3(D_ / 128, NTILES_, 2), 256, 0, stream>>>(act, w2t, part, tileTab);
  k_combine<<<T_, 256, 0, stream>>>(part, rowOf, tokExp, tokW, b2, out);
}